// Round 19
// baseline (78.363 us; speedup 1.0000x reference)
//
#include <hip/hip_runtime.h>

typedef __bf16 bf16x8 __attribute__((ext_vector_type(8)));
typedef float f32x4 __attribute__((ext_vector_type(4)));

typedef const unsigned int __attribute__((address_space(1)))* gptr_t;
typedef unsigned int __attribute__((address_space(3)))* lptr_t;

static __device__ __forceinline__ unsigned short f2bf(float f){
  __bf16 h = (__bf16)f;                     // native v_cvt (RNE)
  return __builtin_bit_cast(unsigned short, h);
}
static __device__ __forceinline__ float bf2f(unsigned short h){
  unsigned int u = ((unsigned int)h) << 16;
  return __builtin_bit_cast(float, u);
}

// ---------------- kernel 0: weights -> transposed bf16 [384][1024] ----------------
__global__ __launch_bounds__(256) void k_prepw(const float* __restrict__ Wq,
                                               const float* __restrict__ Wk,
                                               const float* __restrict__ Wv,
                                               unsigned short* __restrict__ Wtb){
  int idx = blockIdx.x * 256 + threadIdx.x;   // 0 .. 384*1024-1
  int m = idx >> 10;
  int k = idx & 1023;
  const float* W = (m < 128) ? Wq : ((m < 256) ? Wk : Wv);
  int n = m & 127;
  Wtb[idx] = f2bf(W[k * 128 + n]);
}

// ---------------- kernel 1: fused QKV projection + RoPE + V-transpose ----------------
// Round-9 geometry but BK=32 with a 3-buffer counted-vmcnt pipeline (T4):
// buffers are 12 KB so 3 of them (36 KB) keep the grid's 3 blocks/CU resident
// (round-17's 73.7 KB version proved the vmcnt audit correct but lost occupancy).
// Mid-loop barriers use vmcnt(2): this step's 2 VMEM ops (1 A float4 + 1 B gload)
// stay in flight; the tile needed next is a full step older. Never drain mid-loop.
#define QKV_BUF3 6144   // shorts per buffer: 64*32 (A) + 128*32 (B)
__global__ __launch_bounds__(512) void k_qkv(const float* __restrict__ x,
                                             const unsigned short* __restrict__ Wtb,
                                             unsigned short* __restrict__ Qr,
                                             unsigned short* __restrict__ Kr,
                                             unsigned short* __restrict__ Vt){
  __shared__ __align__(16) unsigned short lds[3 * QKV_BUF3];  // 36,864 B -> 3 blocks/CU (grid-capped)

  int bid0 = blockIdx.x;
  int wg = (bid0 & 7) * 96 + (bid0 >> 3);   // XCD-bijective swizzle (768 = 8*96)
  int mblk = wg / 3;
  int nblk = wg - mblk * 3;

  int tid = threadIdx.x;
  int lane = tid & 63, wid = tid >> 6;      // wid 0..7
  int wm = wid >> 1, wn = wid & 1;          // 4 x 2 wave layout (wave = 16 x 64)
  int g = lane >> 4, lr = lane & 15;

  f32x4 acc[4] = {};
  const float* xbase = x + (size_t)(mblk * 64) * 1024;
  const unsigned short* wbase = Wtb + (size_t)(nblk * 128) * 1024;

  // ---- staging maps (k0-invariant) ----
  // A: 512 threads = 64 rows x 8 float4-chunks (4 fp32 -> 8 B bf16);
  //    LDS write addr chunk16-XOR swizzled within the 64 B row.
  int ar = tid >> 3, ac = tid & 7;                 // row, float4 index (cols ac*4)
  const float* agp = xbase + (size_t)ar * 1024 + ac * 4;
  int awoff = ar * 64 + (((ac >> 1) ^ (ar & 3)) << 4) + (ac & 1) * 8; // byte offset in A region
  // B: 512 threads = 128 rows x 4 chunks of 16 B; LDS dest linear (gload_lds),
  //    GLOBAL source pre-swizzled (m173): position bc holds logical chunk bc^(br&3).
  int br = tid >> 2, bc = tid & 3;
  const unsigned short* bgp = wbase + (size_t)br * 1024 + ((bc ^ (br & 3)) << 3);
  int bdoff = 2048 + wid * 512;                    // shorts within buffer (+ lane*16B by HW)

  float4 faA;        // in-flight A for tile t+1 (ds_written next step)
  // ---- prologue: tile 0 staged to buf0; tile 1 issued (A->regs, B->buf1)
  {
    float4 a0 = *reinterpret_cast<const float4*>(agp);
    __builtin_amdgcn_global_load_lds((gptr_t)(const void*)bgp,
                                     (lptr_t)(void*)(lds + bdoff), 16, 0, 0);
    faA = *reinterpret_cast<const float4*>(agp + 32);
    __builtin_amdgcn_global_load_lds((gptr_t)(const void*)(bgp + 32),
                                     (lptr_t)(void*)(lds + QKV_BUF3 + bdoff), 16, 0, 0);
    union { unsigned short s[4]; uint2 u2; } pk;
    pk.s[0] = f2bf(a0.x); pk.s[1] = f2bf(a0.y);
    pk.s[2] = f2bf(a0.z); pk.s[3] = f2bf(a0.w);
    *reinterpret_cast<uint2*>((char*)lds + awoff) = pk.u2;
    // B(0) must be done; faA + B(1) (the 2 newest) stay in flight.
    asm volatile("s_waitcnt vmcnt(2) lgkmcnt(0)" ::: "memory");
    __builtin_amdgcn_s_barrier();
    __builtin_amdgcn_sched_barrier(0);
  }

  for (int t = 0; t < 32; t++){
    unsigned short* bufC = lds + (t % 3) * QKV_BUF3;          // compute tile t
    unsigned short* bufN = lds + ((t + 1) % 3) * QKV_BUF3;    // A late-write (t+1)
    unsigned short* bufF = lds + ((t + 2) % 3) * QKV_BUF3;    // fetch target (t+2)
    float4 fnA = faA;
    if (t < 30){
      int k0n = (t + 2) * 32;
      fnA = *reinterpret_cast<const float4*>(agp + k0n);
      __builtin_amdgcn_global_load_lds((gptr_t)(const void*)(bgp + k0n),
                                       (lptr_t)(void*)(bufF + bdoff), 16, 0, 0);
    }

    // compute tile t from bufC (readied by previous barrier)
    {
      const char* cA = (const char*)bufC;
      const char* cB = cA + 4096;
      int arow = wm * 16 + lr;
      bf16x8 af = *reinterpret_cast<const bf16x8*>(
          cA + arow * 64 + ((g * 16) ^ ((arow & 3) << 4)));
#pragma unroll
      for (int n = 0; n < 4; n++){
        int brow = wn * 64 + n * 16 + lr;
        bf16x8 bn = *reinterpret_cast<const bf16x8*>(
            cB + brow * 64 + ((g * 16) ^ ((brow & 3) << 4)));
        acc[n] = __builtin_amdgcn_mfma_f32_16x16x32_bf16(af, bn, acc[n], 0, 0, 0);
      }
    }

    // late-write A(t+1) from regs (loaded last step), then counted barrier
    if (t < 31){
      union { unsigned short s[4]; uint2 u2; } pk;
      pk.s[0] = f2bf(faA.x); pk.s[1] = f2bf(faA.y);
      pk.s[2] = f2bf(faA.z); pk.s[3] = f2bf(faA.w);
      *reinterpret_cast<uint2*>((char*)bufN + awoff) = pk.u2;

      // tile t+1's B gload + A load were issued at step t-1 -> older than this
      // step's 2 ops -> vmcnt(2) suffices. Tail (t==30): nothing newer -> drain.
      if (t < 30)
        asm volatile("s_waitcnt vmcnt(2) lgkmcnt(0)" ::: "memory");
      else
        asm volatile("s_waitcnt vmcnt(0) lgkmcnt(0)" ::: "memory");
      __builtin_amdgcn_s_barrier();
      __builtin_amdgcn_sched_barrier(0);
    }
    faA = fnA;
  }
  __syncthreads();   // full drain before epilogue LDS reuse

  int row0 = mblk * 64;
  if (nblk < 2){
    // ---- RoPE epilogue -> Qr or Kr ----
    unsigned short* sE = lds;             // [64][136]
    // Q also absorbs 128^-0.5 * log2(e) so attention softmax can use exp2 directly
    float scale = nblk ? 1.0f : 0.12751744950370064f;
#pragma unroll
    for (int n = 0; n < 4; n++){
      int col = wn * 64 + n * 16 + lr;
      int i = col >> 1;
      float theta = exp2f(13.287712379549449f * (2.0f - 2.0f * (float)i) * 0.015625f);
      float sgn = (lr & 1) ? -1.0f : 1.0f;
#pragma unroll
      for (int r = 0; r < 4; r++){
        int tl = wm * 16 + g * 4 + r;
        int t = (row0 + tl) & 2047;
        float s, c;
        sincosf((float)t * theta, &s, &c);
        float v = acc[n][r];
        float partner = __shfl_xor(v, 1);
        float res = (v * c + partner * sgn * s) * scale;
        sE[tl * 136 + col] = f2bf(res);
      }
    }
    __syncthreads();
    unsigned short* dst = (nblk ? Kr : Qr) + (size_t)row0 * 128;
#pragma unroll
    for (int p = 0; p < 2; p++){
      int u = tid + p * 512;              // 0..1023
      int tl = u >> 4, h0 = (u & 15) * 8;
      uint4 vv = *reinterpret_cast<const uint4*>(&sE[tl * 136 + h0]);
      *reinterpret_cast<uint4*>(dst + (size_t)tl * 128 + h0) = vv;
    }
  } else {
    // ---- V epilogue: transpose -> Vt[b][h][t] ----
    unsigned short* sE = lds;             // [128][72]
#pragma unroll
    for (int n = 0; n < 4; n++){
      int col = wn * 64 + n * 16 + lr;
#pragma unroll
      for (int r = 0; r < 4; r++){
        int tl = wm * 16 + g * 4 + r;
        sE[col * 72 + tl] = f2bf(acc[n][r]);
      }
    }
    __syncthreads();
    int b = row0 >> 11;
    int t0 = row0 & 2047;
#pragma unroll
    for (int p = 0; p < 2; p++){
      int u = tid + p * 512;              // 0..1023
      int h = u >> 3, tc = (u & 7) * 8;
      uint4 vv = *reinterpret_cast<const uint4*>(&sE[h * 72 + tc]);
      *reinterpret_cast<uint4*>(Vt + ((size_t)(b * 128 + h)) * 2048 + t0 + tc) = vv;
    }
  }
}

// ---------------- kernel 2: causal flash attention, split-KV partials ----------------
// (round-16 config: direct staging + setprio around MFMA clusters)
__global__ __launch_bounds__(128) void k_attn_part(const unsigned short* __restrict__ Qr,
                                                   const unsigned short* __restrict__ Kr,
                                                   const unsigned short* __restrict__ Vt,
                                                   unsigned short* __restrict__ Opart,
                                                   float* __restrict__ ml){
  __shared__ __align__(16) unsigned short sK[32][136];   // [kv][h]
  __shared__ __align__(16) unsigned short sV[128][40];   // [h][kv]
  __shared__ __align__(16) unsigned short sP[2][16][40]; // per-wave P^T [q][kv]

  int bid = blockIdx.x;
  int b = bid / 160;
  int rem = bid - b * 160;
  int qt, c;
  if (rem < 16)      { qt = rem;                    c = 0; }
  else if (rem < 48) { qt = 16 + ((rem - 16) >> 1); c = (rem - 16) & 1; }
  else if (rem < 96) { int r2 = rem - 48; int d = r2 / 3; qt = 32 + d; c = r2 - 3 * d; }
  else               { int r3 = rem - 96; qt = 48 + (r3 >> 2); c = r3 & 3; }

  int q_base = qt * 32;
  int kv_start = c * 512;
  int kv_end = min(kv_start + 512, q_base + 32);
  int niter = (kv_end - kv_start) >> 5;

  int tid = threadIdx.x, w = tid >> 6, lane = tid & 63;
  int g = lane >> 4, lr = lane & 15;

  int qrow = q_base + w * 16 + lr;          // this lane's q row
  const unsigned short* qptr = Qr + ((size_t)(b * 2048 + qrow)) * 128;
  bf16x8 qf[4];
#pragma unroll
  for (int hc = 0; hc < 4; hc++)
    qf[hc] = *reinterpret_cast<const bf16x8*>(qptr + hc * 32 + g * 8);

  f32x4 oacc[8] = {};
  float mrow = -1e30f, lrow = 0.0f;         // per-lane (q = qrow)

  const unsigned short* Kb = Kr + (size_t)b * 2048 * 128;
  const unsigned short* Vb = Vt + (size_t)b * 128 * 2048;

  for (int it = 0; it < niter; it++){
    int kv0 = kv_start + it * 32;
    __syncthreads();
#pragma unroll
    for (int p = 0; p < 4; p++){
      int idx = tid + p * 128;               // 0..511
      int r = idx >> 4, c8 = (idx & 15) * 8;
      *reinterpret_cast<uint4*>(&sK[r][c8]) =
        *reinterpret_cast<const uint4*>(Kb + (size_t)(kv0 + r) * 128 + c8);
    }
#pragma unroll
    for (int p = 0; p < 4; p++){
      int idx = tid + p * 128;               // 0..511
      int h = idx >> 2, c8 = (idx & 3) * 8;
      *reinterpret_cast<uint4*>(&sV[h][c8]) =
        *reinterpret_cast<const uint4*>(Vb + (size_t)h * 2048 + kv0 + c8);
    }
    __syncthreads();

    // swapped QK^T: S^T, col = q (lr), row = kv (4g+r), 2 kv tiles of 16
    f32x4 st[2];
    __builtin_amdgcn_s_setprio(1);
#pragma unroll
    for (int ct = 0; ct < 2; ct++){
      f32x4 a = {0.f, 0.f, 0.f, 0.f};
#pragma unroll
      for (int hc = 0; hc < 4; hc++){
        bf16x8 kf = *reinterpret_cast<const bf16x8*>(&sK[ct * 16 + lr][hc * 32 + g * 8]);
        a = __builtin_amdgcn_mfma_f32_16x16x32_bf16(kf, qf[hc], a, 0, 0, 0);
      }
      st[ct] = a;
    }
    __builtin_amdgcn_s_setprio(0);

    // per-lane mask + max (scores already in log2 domain)
    float mx = -1e30f;
#pragma unroll
    for (int ct = 0; ct < 2; ct++){
      int kvb = kv0 + ct * 16 + g * 4;
#pragma unroll
      for (int r = 0; r < 4; r++){
        float s = (kvb + r <= qrow) ? st[ct][r] : -1e30f;
        st[ct][r] = s;
        mx = fmaxf(mx, s);
      }
    }
    mx = fmaxf(mx, __shfl_xor(mx, 16));
    mx = fmaxf(mx, __shfl_xor(mx, 32));
    float m = fmaxf(mrow, mx);
    float alpha = exp2f(mrow - m);

    float rs = 0.0f;
#pragma unroll
    for (int ct = 0; ct < 2; ct++){
      float p0 = exp2f(st[ct][0] - m);
      float p1 = exp2f(st[ct][1] - m);
      float p2 = exp2f(st[ct][2] - m);
      float p3 = exp2f(st[ct][3] - m);
      rs += (p0 + p1) + (p2 + p3);
      uint2 pk;
      pk.x = ((unsigned int)f2bf(p1) << 16) | f2bf(p0);
      pk.y = ((unsigned int)f2bf(p3) << 16) | f2bf(p2);
      *reinterpret_cast<uint2*>(&sP[w][lr][ct * 16 + g * 4]) = pk;
    }
    rs += __shfl_xor(rs, 16);
    rs += __shfl_xor(rs, 32);
    lrow = lrow * alpha + rs;
    mrow = m;

    // rescale O: gather alpha for q-local = 4g+r
    float af0 = __shfl(alpha, g * 4 + 0);
    float af1 = __shfl(alpha, g * 4 + 1);
    float af2 = __shfl(alpha, g * 4 + 2);
    float af3 = __shfl(alpha, g * 4 + 3);
#pragma unroll
    for (int ht = 0; ht < 8; ht++){
      oacc[ht][0] *= af0;
      oacc[ht][1] *= af1;
      oacc[ht][2] *= af2;
      oacc[ht][3] *= af3;
    }

    // PV: O[16 q][128 h] += P[16][32] @ V[32][128]
    bf16x8 pa = *reinterpret_cast<const bf16x8*>(&sP[w][lr][g * 8]);
    __builtin_amdgcn_s_setprio(1);
#pragma unroll
    for (int ht = 0; ht < 8; ht++){
      bf16x8 vf = *reinterpret_cast<const bf16x8*>(&sV[ht * 16 + lr][g * 8]);
      oacc[ht] = __builtin_amdgcn_mfma_f32_16x16x32_bf16(pa, vf, oacc[ht], 0, 0, 0);
    }
    __builtin_amdgcn_s_setprio(0);
  }

  size_t slot = (size_t)(b * 64 + qt) * 4 + c;
  unsigned short* op = Opart + slot * 4096;
  float* mlp = ml + slot * 64;
#pragma unroll
  for (int ht = 0; ht < 8; ht++)
#pragma unroll
    for (int r = 0; r < 4; r++){
      int rowl = w * 16 + g * 4 + r;
      op[rowl * 128 + ht * 16 + lr] = f2bf(oacc[ht][r]);
    }
  if (lane < 16){
    mlp[w * 16 + lr]      = mrow;
    mlp[32 + w * 16 + lr] = lrow;
  }
}

// ---------------- kernel 3: combine partials ----------------
__global__ __launch_bounds__(256) void k_comb(const unsigned short* __restrict__ Opart,
                                              const float* __restrict__ ml,
                                              float* __restrict__ out){
  int bid = blockIdx.x;          // 512 = 8 b * 64 qt
  int b = bid >> 6, qt = bid & 63;
  int nck = (qt >> 4) + 1;
  int tid = threadIdx.x;
  int row = tid >> 3;
  int col0 = (tid & 7) * 16;
  size_t slot0 = (size_t)(b * 64 + qt) * 4;

  float m_c[4], l_c[4];
  float M = -1e30f;
#pragma unroll
  for (int c = 0; c < 4; c++) if (c < nck){
    m_c[c] = ml[(slot0 + c) * 64 + row];
    l_c[c] = ml[(slot0 + c) * 64 + 32 + row];
    M = fmaxf(M, m_c[c]);
  }
  float L = 0.0f, wgt[4];
#pragma unroll
  for (int c = 0; c < 4; c++) if (c < nck){
    wgt[c] = exp2f(m_c[c] - M);        // m is in log2 domain
    L += wgt[c] * l_c[c];
  }
  float acc[16] = {};
#pragma unroll
  for (int c = 0; c < 4; c++) if (c < nck){
    const unsigned short* src = Opart + (slot0 + c) * 4096 + row * 128 + col0;
    uint4 u0 = *reinterpret_cast<const uint4*>(src);
    uint4 u1 = *reinterpret_cast<const uint4*>(src + 8);
    unsigned int uu[8] = {u0.x, u0.y, u0.z, u0.w, u1.x, u1.y, u1.z, u1.w};
#pragma unroll
    for (int j = 0; j < 8; j++){
      acc[2 * j]     += wgt[c] * bf2f((unsigned short)(uu[j] & 0xFFFF));
      acc[2 * j + 1] += wgt[c] * bf2f((unsigned short)(uu[j] >> 16));
    }
  }
  float invL = 1.0f / L;
  float* dst = out + ((size_t)(b * 2048 + qt * 32 + row)) * 128 + col0;
#pragma unroll
  for (int j = 0; j < 4; j++){
    float4 v = {acc[4 * j] * invL, acc[4 * j + 1] * invL,
                acc[4 * j + 2] * invL, acc[4 * j + 3] * invL};
    *reinterpret_cast<float4*>(dst + 4 * j) = v;
  }
}

extern "C" void kernel_launch(void* const* d_in, const int* in_sizes, int n_in,
                              void* d_out, int out_size, void* d_ws, size_t ws_size,
                              hipStream_t stream) {
  const float* x  = (const float*)d_in[0];
  const float* Wq = (const float*)d_in[1];
  const float* Wk = (const float*)d_in[2];
  const float* Wv = (const float*)d_in[3];
  float* out = (float*)d_out;

  char* ws = (char*)d_ws;
  unsigned short* Wtb   = (unsigned short*)ws;                         //   786,432 B
  unsigned short* Qr    = (unsigned short*)(ws + 786432);              // 4,194,304 B
  unsigned short* Kr    = (unsigned short*)(ws + 786432 + 4194304);    // 4,194,304 B
  unsigned short* Vt    = (unsigned short*)(ws + 786432 + 2*4194304);  // 4,194,304 B
  unsigned short* Opart = (unsigned short*)(ws + 786432 + 3*4194304);  // 16,777,216 B
  float* ml             = (float*)(ws + 786432 + 3*4194304 + 16777216);//    524,288 B

  hipLaunchKernelGGL(k_prepw, dim3(1536), dim3(256), 0, stream, Wq, Wk, Wv, Wtb);
  hipLaunchKernelGGL(k_qkv,   dim3(768),  dim3(512), 0, stream, x, Wtb, Qr, Kr, Vt);
  hipLaunchKernelGGL(k_attn_part, dim3(1280), dim3(128), 0, stream, Qr, Kr, Vt, Opart, ml);
  hipLaunchKernelGGL(k_comb, dim3(512), dim3(256), 0, stream, Opart, ml, out);
}

// Round 20
// 75.015 us; speedup vs baseline: 1.0446x; 1.0446x over previous
//
#include <hip/hip_runtime.h>

typedef __bf16 bf16x8 __attribute__((ext_vector_type(8)));
typedef float f32x4 __attribute__((ext_vector_type(4)));

typedef const unsigned int __attribute__((address_space(1)))* gptr_t;
typedef unsigned int __attribute__((address_space(3)))* lptr_t;

static __device__ __forceinline__ unsigned short f2bf(float f){
  __bf16 h = (__bf16)f;                     // native v_cvt (RNE)
  return __builtin_bit_cast(unsigned short, h);
}
static __device__ __forceinline__ float bf2f(unsigned short h){
  unsigned int u = ((unsigned int)h) << 16;
  return __builtin_bit_cast(float, u);
}

// ---------------- kernel 0: weights -> transposed bf16 [384][1024] ----------------
__global__ __launch_bounds__(256) void k_prepw(const float* __restrict__ Wq,
                                               const float* __restrict__ Wk,
                                               const float* __restrict__ Wv,
                                               unsigned short* __restrict__ Wtb){
  int idx = blockIdx.x * 256 + threadIdx.x;   // 0 .. 384*1024-1
  int m = idx >> 10;
  int k = idx & 1023;
  const float* W = (m < 128) ? Wq : ((m < 256) ? Wk : Wv);
  int n = m & 127;
  Wtb[idx] = f2bf(W[k * 128 + n]);
}

// ---------------- kernel 1: fused QKV projection + RoPE + V-transpose ----------------
// (round-9 config, frozen: best of 9 structural variants, rounds 6-19)
#define QKV_BUFS 12288   // shorts per buffer: 64*64 (A) + 128*64 (B)
__global__ __launch_bounds__(512) void k_qkv(const float* __restrict__ x,
                                             const unsigned short* __restrict__ Wtb,
                                             unsigned short* __restrict__ Qr,
                                             unsigned short* __restrict__ Kr,
                                             unsigned short* __restrict__ Vt){
  __shared__ __align__(16) unsigned short lds[2 * QKV_BUFS];  // 49,152 B -> 3 blocks/CU

  int bid0 = blockIdx.x;
  int wg = (bid0 & 7) * 96 + (bid0 >> 3);   // XCD-bijective swizzle (768 = 8*96)
  int mblk = wg / 3;
  int nblk = wg - mblk * 3;

  int tid = threadIdx.x;
  int lane = tid & 63, wid = tid >> 6;      // wid 0..7
  int wm = wid >> 1, wn = wid & 1;          // 4 x 2 wave layout
  int g = lane >> 4, lr = lane & 15;

  f32x4 acc[4] = {};
  const float* xbase = x + (size_t)(mblk * 64) * 1024;
  const unsigned short* wbase = Wtb + (size_t)(nblk * 128) * 1024;

  // A: 512 threads = 64 rows x 8 chunks; global linear, LDS WRITE addr swizzled
  int ar = tid >> 3, ac = tid & 7;
  const float* agp = xbase + (size_t)ar * 1024 + ac * 8;
  int awoff = ar * 128 + ((ac ^ (ar & 7)) << 4);   // byte offset within A tile
  // B: LDS dest linear (gload_lds), GLOBAL source pre-swizzled (m173)
  int bp = tid & 7;
  int br1 = tid >> 3, br2 = br1 + 64;
  const unsigned short* bgp1 = wbase + (size_t)br1 * 1024 + ((bp ^ (br1 & 7)) << 3);
  const unsigned short* bgp2 = wbase + (size_t)br2 * 1024 + ((bp ^ (br2 & 7)) << 3);
  int bdoff1 = wid * 512;          // shorts within B region (+ lane*16B by HW)
  int bdoff2 = 4096 + wid * 512;

  // prologue: stage tile 0 into buffer 0
  {
    unsigned short* sB = lds + 4096;
    __builtin_amdgcn_global_load_lds((gptr_t)(const void*)bgp1,
                                     (lptr_t)(void*)(sB + bdoff1), 16, 0, 0);
    __builtin_amdgcn_global_load_lds((gptr_t)(const void*)bgp2,
                                     (lptr_t)(void*)(sB + bdoff2), 16, 0, 0);
    float4 v0 = *reinterpret_cast<const float4*>(agp);
    float4 v1 = *reinterpret_cast<const float4*>(agp + 4);
    union { bf16x8 h; uint4 u4; } pk;
    pk.h[0] = (__bf16)v0.x; pk.h[1] = (__bf16)v0.y;
    pk.h[2] = (__bf16)v0.z; pk.h[3] = (__bf16)v0.w;
    pk.h[4] = (__bf16)v1.x; pk.h[5] = (__bf16)v1.y;
    pk.h[6] = (__bf16)v1.z; pk.h[7] = (__bf16)v1.w;
    *reinterpret_cast<uint4*>((char*)lds + awoff) = pk.u4;
    __syncthreads();
  }

  int cur = 0;
  float4 fa0, fa1;
  for (int t = 0; t < 16; t++){
    // issue next tile's staging BEFORE compute; latency hides under MFMA
    if (t < 15){
      int k0n = (t + 1) * 64;
      unsigned short* sB = lds + (cur ^ 1) * QKV_BUFS + 4096;
      __builtin_amdgcn_global_load_lds((gptr_t)(const void*)(bgp1 + k0n),
                                       (lptr_t)(void*)(sB + bdoff1), 16, 0, 0);
      __builtin_amdgcn_global_load_lds((gptr_t)(const void*)(bgp2 + k0n),
                                       (lptr_t)(void*)(sB + bdoff2), 16, 0, 0);
      fa0 = *reinterpret_cast<const float4*>(agp + k0n);
      fa1 = *reinterpret_cast<const float4*>(agp + k0n + 4);
    }

    // compute from buf[cur]
    {
      const char* cA = (const char*)(lds + cur * QKV_BUFS);
      const char* cB = cA + 8192;
      int arow = wm * 16 + lr;
      int asw = (arow & 7) << 4;
#pragma unroll
      for (int ks = 0; ks < 2; ks++){
        bf16x8 af = *reinterpret_cast<const bf16x8*>(
            cA + arow * 128 + ((ks * 64 + g * 16) ^ asw));
#pragma unroll
        for (int n = 0; n < 4; n++){
          int brow = wn * 64 + n * 16 + lr;
          bf16x8 bn = *reinterpret_cast<const bf16x8*>(
              cB + brow * 128 + ((ks * 64 + g * 16) ^ ((brow & 7) << 4)));
          acc[n] = __builtin_amdgcn_mfma_f32_16x16x32_bf16(af, bn, acc[n], 0, 0, 0);
        }
      }
    }

    // write A into next buffer (loads arrived during compute), single barrier
    if (t < 15){
      union { bf16x8 h; uint4 u4; } pk;
      pk.h[0] = (__bf16)fa0.x; pk.h[1] = (__bf16)fa0.y;
      pk.h[2] = (__bf16)fa0.z; pk.h[3] = (__bf16)fa0.w;
      pk.h[4] = (__bf16)fa1.x; pk.h[5] = (__bf16)fa1.y;
      pk.h[6] = (__bf16)fa1.z; pk.h[7] = (__bf16)fa1.w;
      *reinterpret_cast<uint4*>((char*)(lds + (cur ^ 1) * QKV_BUFS) + awoff) = pk.u4;
    }
    __syncthreads();
    cur ^= 1;
  }

  int row0 = mblk * 64;
  if (nblk < 2){
    // ---- RoPE epilogue -> Qr or Kr ----
    unsigned short* sE = lds;             // [64][136]
    // Q also absorbs 128^-0.5 * log2(e) so attention softmax can use exp2 directly
    float scale = nblk ? 1.0f : 0.12751744950370064f;
#pragma unroll
    for (int n = 0; n < 4; n++){
      int col = wn * 64 + n * 16 + lr;
      int i = col >> 1;
      float theta = exp2f(13.287712379549449f * (2.0f - 2.0f * (float)i) * 0.015625f);
      float sgn = (lr & 1) ? -1.0f : 1.0f;
#pragma unroll
      for (int r = 0; r < 4; r++){
        int tl = wm * 16 + g * 4 + r;
        int t = (row0 + tl) & 2047;
        float s, c;
        sincosf((float)t * theta, &s, &c);
        float v = acc[n][r];
        float partner = __shfl_xor(v, 1);
        float res = (v * c + partner * sgn * s) * scale;
        sE[tl * 136 + col] = f2bf(res);
      }
    }
    __syncthreads();
    unsigned short* dst = (nblk ? Kr : Qr) + (size_t)row0 * 128;
#pragma unroll
    for (int p = 0; p < 2; p++){
      int u = tid + p * 512;              // 0..1023
      int tl = u >> 4, h0 = (u & 15) * 8;
      uint4 vv = *reinterpret_cast<const uint4*>(&sE[tl * 136 + h0]);
      *reinterpret_cast<uint4*>(dst + (size_t)tl * 128 + h0) = vv;
    }
  } else {
    // ---- V epilogue: transpose -> Vt[b][h][t] ----
    unsigned short* sE = lds;             // [128][72]
#pragma unroll
    for (int n = 0; n < 4; n++){
      int col = wn * 64 + n * 16 + lr;
#pragma unroll
      for (int r = 0; r < 4; r++){
        int tl = wm * 16 + g * 4 + r;
        sE[col * 72 + tl] = f2bf(acc[n][r]);
      }
    }
    __syncthreads();
    int b = row0 >> 11;
    int t0 = row0 & 2047;
#pragma unroll
    for (int p = 0; p < 2; p++){
      int u = tid + p * 512;              // 0..1023
      int h = u >> 3, tc = (u & 7) * 8;
      uint4 vv = *reinterpret_cast<const uint4*>(&sE[h * 72 + tc]);
      *reinterpret_cast<uint4*>(Vt + ((size_t)(b * 128 + h)) * 2048 + t0 + tc) = vv;
    }
  }
}

// ---------------- kernel 2: causal flash attention, split-KV partials ----------------
// Round-16 config (direct staging + setprio around MFMA clusters) — session best.
__global__ __launch_bounds__(128) void k_attn_part(const unsigned short* __restrict__ Qr,
                                                   const unsigned short* __restrict__ Kr,
                                                   const unsigned short* __restrict__ Vt,
                                                   unsigned short* __restrict__ Opart,
                                                   float* __restrict__ ml){
  __shared__ __align__(16) unsigned short sK[32][136];   // [kv][h]
  __shared__ __align__(16) unsigned short sV[128][40];   // [h][kv]
  __shared__ __align__(16) unsigned short sP[2][16][40]; // per-wave P^T [q][kv]

  int bid = blockIdx.x;
  int b = bid / 160;
  int rem = bid - b * 160;
  int qt, c;
  if (rem < 16)      { qt = rem;                    c = 0; }
  else if (rem < 48) { qt = 16 + ((rem - 16) >> 1); c = (rem - 16) & 1; }
  else if (rem < 96) { int r2 = rem - 48; int d = r2 / 3; qt = 32 + d; c = r2 - 3 * d; }
  else               { int r3 = rem - 96; qt = 48 + (r3 >> 2); c = r3 & 3; }

  int q_base = qt * 32;
  int kv_start = c * 512;
  int kv_end = min(kv_start + 512, q_base + 32);
  int niter = (kv_end - kv_start) >> 5;

  int tid = threadIdx.x, w = tid >> 6, lane = tid & 63;
  int g = lane >> 4, lr = lane & 15;

  int qrow = q_base + w * 16 + lr;          // this lane's q row
  const unsigned short* qptr = Qr + ((size_t)(b * 2048 + qrow)) * 128;
  bf16x8 qf[4];
#pragma unroll
  for (int hc = 0; hc < 4; hc++)
    qf[hc] = *reinterpret_cast<const bf16x8*>(qptr + hc * 32 + g * 8);

  f32x4 oacc[8] = {};
  float mrow = -1e30f, lrow = 0.0f;         // per-lane (q = qrow)

  const unsigned short* Kb = Kr + (size_t)b * 2048 * 128;
  const unsigned short* Vb = Vt + (size_t)b * 128 * 2048;

  for (int it = 0; it < niter; it++){
    int kv0 = kv_start + it * 32;
    __syncthreads();
#pragma unroll
    for (int p = 0; p < 4; p++){
      int idx = tid + p * 128;               // 0..511
      int r = idx >> 4, c8 = (idx & 15) * 8;
      *reinterpret_cast<uint4*>(&sK[r][c8]) =
        *reinterpret_cast<const uint4*>(Kb + (size_t)(kv0 + r) * 128 + c8);
    }
#pragma unroll
    for (int p = 0; p < 4; p++){
      int idx = tid + p * 128;               // 0..511
      int h = idx >> 2, c8 = (idx & 3) * 8;
      *reinterpret_cast<uint4*>(&sV[h][c8]) =
        *reinterpret_cast<const uint4*>(Vb + (size_t)h * 2048 + kv0 + c8);
    }
    __syncthreads();

    // swapped QK^T: S^T, col = q (lr), row = kv (4g+r), 2 kv tiles of 16
    f32x4 st[2];
    __builtin_amdgcn_s_setprio(1);
#pragma unroll
    for (int ct = 0; ct < 2; ct++){
      f32x4 a = {0.f, 0.f, 0.f, 0.f};
#pragma unroll
      for (int hc = 0; hc < 4; hc++){
        bf16x8 kf = *reinterpret_cast<const bf16x8*>(&sK[ct * 16 + lr][hc * 32 + g * 8]);
        a = __builtin_amdgcn_mfma_f32_16x16x32_bf16(kf, qf[hc], a, 0, 0, 0);
      }
      st[ct] = a;
    }
    __builtin_amdgcn_s_setprio(0);

    // per-lane mask + max (scores already in log2 domain)
    float mx = -1e30f;
#pragma unroll
    for (int ct = 0; ct < 2; ct++){
      int kvb = kv0 + ct * 16 + g * 4;
#pragma unroll
      for (int r = 0; r < 4; r++){
        float s = (kvb + r <= qrow) ? st[ct][r] : -1e30f;
        st[ct][r] = s;
        mx = fmaxf(mx, s);
      }
    }
    mx = fmaxf(mx, __shfl_xor(mx, 16));
    mx = fmaxf(mx, __shfl_xor(mx, 32));
    float m = fmaxf(mrow, mx);
    float alpha = exp2f(mrow - m);

    float rs = 0.0f;
#pragma unroll
    for (int ct = 0; ct < 2; ct++){
      float p0 = exp2f(st[ct][0] - m);
      float p1 = exp2f(st[ct][1] - m);
      float p2 = exp2f(st[ct][2] - m);
      float p3 = exp2f(st[ct][3] - m);
      rs += (p0 + p1) + (p2 + p3);
      uint2 pk;
      pk.x = ((unsigned int)f2bf(p1) << 16) | f2bf(p0);
      pk.y = ((unsigned int)f2bf(p3) << 16) | f2bf(p2);
      *reinterpret_cast<uint2*>(&sP[w][lr][ct * 16 + g * 4]) = pk;
    }
    rs += __shfl_xor(rs, 16);
    rs += __shfl_xor(rs, 32);
    lrow = lrow * alpha + rs;
    mrow = m;

    // rescale O: gather alpha for q-local = 4g+r
    float af0 = __shfl(alpha, g * 4 + 0);
    float af1 = __shfl(alpha, g * 4 + 1);
    float af2 = __shfl(alpha, g * 4 + 2);
    float af3 = __shfl(alpha, g * 4 + 3);
#pragma unroll
    for (int ht = 0; ht < 8; ht++){
      oacc[ht][0] *= af0;
      oacc[ht][1] *= af1;
      oacc[ht][2] *= af2;
      oacc[ht][3] *= af3;
    }

    // PV: O[16 q][128 h] += P[16][32] @ V[32][128]
    bf16x8 pa = *reinterpret_cast<const bf16x8*>(&sP[w][lr][g * 8]);
    __builtin_amdgcn_s_setprio(1);
#pragma unroll
    for (int ht = 0; ht < 8; ht++){
      bf16x8 vf = *reinterpret_cast<const bf16x8*>(&sV[ht * 16 + lr][g * 8]);
      oacc[ht] = __builtin_amdgcn_mfma_f32_16x16x32_bf16(pa, vf, oacc[ht], 0, 0, 0);
    }
    __builtin_amdgcn_s_setprio(0);
  }

  size_t slot = (size_t)(b * 64 + qt) * 4 + c;
  unsigned short* op = Opart + slot * 4096;
  float* mlp = ml + slot * 64;
#pragma unroll
  for (int ht = 0; ht < 8; ht++)
#pragma unroll
    for (int r = 0; r < 4; r++){
      int rowl = w * 16 + g * 4 + r;
      op[rowl * 128 + ht * 16 + lr] = f2bf(oacc[ht][r]);
    }
  if (lane < 16){
    mlp[w * 16 + lr]      = mrow;
    mlp[32 + w * 16 + lr] = lrow;
  }
}

// ---------------- kernel 3: combine partials ----------------
__global__ __launch_bounds__(256) void k_comb(const unsigned short* __restrict__ Opart,
                                              const float* __restrict__ ml,
                                              float* __restrict__ out){
  int bid = blockIdx.x;          // 512 = 8 b * 64 qt
  int b = bid >> 6, qt = bid & 63;
  int nck = (qt >> 4) + 1;
  int tid = threadIdx.x;
  int row = tid >> 3;
  int col0 = (tid & 7) * 16;
  size_t slot0 = (size_t)(b * 64 + qt) * 4;

  float m_c[4], l_c[4];
  float M = -1e30f;
#pragma unroll
  for (int c = 0; c < 4; c++) if (c < nck){
    m_c[c] = ml[(slot0 + c) * 64 + row];
    l_c[c] = ml[(slot0 + c) * 64 + 32 + row];
    M = fmaxf(M, m_c[c]);
  }
  float L = 0.0f, wgt[4];
#pragma unroll
  for (int c = 0; c < 4; c++) if (c < nck){
    wgt[c] = exp2f(m_c[c] - M);        // m is in log2 domain
    L += wgt[c] * l_c[c];
  }
  float acc[16] = {};
#pragma unroll
  for (int c = 0; c < 4; c++) if (c < nck){
    const unsigned short* src = Opart + (slot0 + c) * 4096 + row * 128 + col0;
    uint4 u0 = *reinterpret_cast<const uint4*>(src);
    uint4 u1 = *reinterpret_cast<const uint4*>(src + 8);
    unsigned int uu[8] = {u0.x, u0.y, u0.z, u0.w, u1.x, u1.y, u1.z, u1.w};
#pragma unroll
    for (int j = 0; j < 8; j++){
      acc[2 * j]     += wgt[c] * bf2f((unsigned short)(uu[j] & 0xFFFF));
      acc[2 * j + 1] += wgt[c] * bf2f((unsigned short)(uu[j] >> 16));
    }
  }
  float invL = 1.0f / L;
  float* dst = out + ((size_t)(b * 2048 + qt * 32 + row)) * 128 + col0;
#pragma unroll
  for (int j = 0; j < 4; j++){
    float4 v = {acc[4 * j] * invL, acc[4 * j + 1] * invL,
                acc[4 * j + 2] * invL, acc[4 * j + 3] * invL};
    *reinterpret_cast<float4*>(dst + 4 * j) = v;
  }
}

extern "C" void kernel_launch(void* const* d_in, const int* in_sizes, int n_in,
                              void* d_out, int out_size, void* d_ws, size_t ws_size,
                              hipStream_t stream) {
  const float* x  = (const float*)d_in[0];
  const float* Wq = (const float*)d_in[1];
  const float* Wk = (const float*)d_in[2];
  const float* Wv = (const float*)d_in[3];
  float* out = (float*)d_out;

  char* ws = (char*)d_ws;
  unsigned short* Wtb   = (unsigned short*)ws;                         //   786,432 B
  unsigned short* Qr    = (unsigned short*)(ws + 786432);              // 4,194,304 B
  unsigned short* Kr    = (unsigned short*)(ws + 786432 + 4194304);    // 4,194,304 B
  unsigned short* Vt    = (unsigned short*)(ws + 786432 + 2*4194304);  // 4,194,304 B
  unsigned short* Opart = (unsigned short*)(ws + 786432 + 3*4194304);  // 16,777,216 B
  float* ml             = (float*)(ws + 786432 + 3*4194304 + 16777216);//    524,288 B

  hipLaunchKernelGGL(k_prepw, dim3(1536), dim3(256), 0, stream, Wq, Wk, Wv, Wtb);
  hipLaunchKernelGGL(k_qkv,   dim3(768),  dim3(512), 0, stream, x, Wtb, Qr, Kr, Vt);
  hipLaunchKernelGGL(k_attn_part, dim3(1280), dim3(128), 0, stream, Qr, Kr, Vt, Opart, ml);
  hipLaunchKernelGGL(k_comb, dim3(512), dim3(256), 0, stream, Opart, ml, out);
}